// Round 12
// baseline (46.950 us; speedup 1.0000x reference)
//
#include <hip/hip_runtime.h>
#include <hip/hip_cooperative_groups.h>
#include <math.h>

namespace cg = cooperative_groups;

#define M_SAMPLES 131072
#define BLK 256
#define NBLK (M_SAMPLES / (BLK * 2))   // 256 blocks, 2 samples/thread, 1 block/CU

typedef float v2f __attribute__((ext_vector_type(2)));

__device__ __forceinline__ v2f swapneg(v2f b) { return (v2f){-b.y, b.x}; }

__device__ __forceinline__ float logaddexp_f(float a, float b) {
    float m = fmaxf(a, b);
    float d = fminf(a, b) - m;
    return m + __logf(1.f + __expf(d));
}

// C(m,k) table (rodata; runtime-indexed loads are memory, not registers)
__device__ const float BINOM[8][8] = {
  {1,0,0,0,0,0,0,0},{1,1,0,0,0,0,0,0},{1,2,1,0,0,0,0,0},{1,3,3,1,0,0,0,0},
  {1,4,6,4,1,0,0,0},{1,5,10,10,5,1,0,0},{1,6,15,20,15,6,1,0},{1,7,21,35,35,21,7,1}};

// Full per-sample pipeline, complex values as packed float2 (v_pk_* f32 ops).
__device__ __forceinline__ float3 eval_sample(
    float t, const v2f (*sA2)[8], const v2f* __restrict__ sPA)
{
    // T_j via Horner (ascending storage f[7-j] = T_j), monic f_8 = 1.
    v2f f[9];
#pragma unroll
    for (int j = 0; j < 8; ++j) {
        v2f p = sA2[7][j];
#pragma unroll
        for (int m = 6; m >= 0; --m) p = p * t + sA2[m][j];
        f[7 - j] = p;
    }
    f[8] = (v2f){1.f, 0.f};

    // speed^2 / accel^2: one packed real Horner
    v2f pa = sPA[12];
#pragma unroll
    for (int d = 11; d >= 0; --d) pa = pa * t + sPA[d];
    const float sp2 = fmaxf(pa.x, 0.f);
    const float ac2 = fmaxf(pa.y, 0.f);
    const float speed = sqrtf(sp2);

    // u_k = k * f_k  (g_j = f'_j = u_{j+1}); us = swapneg(u) for complex mul
    v2f u[9], us[9];
#pragma unroll
    for (int k = 1; k < 9; ++k) { u[k] = (float)k * f[k]; us[k] = swapneg(u[k]); }

    // Bezout matrix B (8x8 complex symmetric): |det B| = |Res(f,f')| (f monic).
    v2f B[8][8], c[8][8];
#pragma unroll
    for (int j = 0; j < 8; ++j) B[7][j] = u[j + 1];
#pragma unroll
    for (int i = 7; i >= 1; --i) {
#pragma unroll
        for (int j = 0; j < i; ++j) {   // fresh pairs (j, i)
            c[j][i] = (f[j].x * u[i + 1] + f[j].y * us[i + 1])
                    - (f[i].x * u[j + 1] + f[i].y * us[j + 1]);
        }
#pragma unroll
        for (int j = 0; j < 8; ++j) {
            v2f cr;
            if (i < j)      cr = c[i][j];
            else if (i > j) cr = -c[j][i];
            else            cr = (v2f){0.f, 0.f};
            if (j >= 1) cr += B[i][j - 1];
            B[i - 1][j] = cr;
        }
    }

    // Pivot-free complex-symmetric LDL^T, upper triangle (R5-identical order).
    float logm = 1.f; int loge = 0;
#pragma unroll
    for (int k = 0; k < 8; ++k) {
        v2f d = B[k][k];
        float pm2 = d.x * d.x + d.y * d.y;
        unsigned ub = __float_as_uint(pm2);
        loge += (int)(ub >> 23) - 126;
        logm *= __uint_as_float((ub & 0x007fffffu) | 0x3f000000u);  // [0.5,1)
        if (k < 7) {
            float is = __builtin_amdgcn_rcpf(pm2);
            is = (pm2 > 1e-30f) ? is : 0.f;
            v2f iv = (v2f){d.x * is, -d.y * is};          // 1/d
            v2f ivs = swapneg(iv);
            v2f w[8], bs[8];
#pragma unroll
            for (int i = k + 1; i < 8; ++i) {
                v2f a = B[k][i];                          // A[i][k] by symmetry
                w[i] = a.x * iv + a.y * ivs;              // w_i = a (x) 1/d
                bs[i] = swapneg(a);
            }
#pragma unroll
            for (int i = k + 1; i < 8; ++i) {
#pragma unroll
                for (int j = i; j < 8; ++j) {
                    B[i][j] = B[i][j] - w[i].x * B[k][j] - w[i].y * bs[j];
                }
            }
        }
    }
    float logdet = 0.5f * (__logf(logm) + (float)loge * 0.69314718055994531f);

    const float LOG_DISC_EPS = -27.63102111592855f;   // ln 1e-12
    const float LOG_DELTA2  = -27.63102111592855f;    // 2 ln 1e-6
    const float LOG1P_LEAD  = 1e-12f;                 // log(1 + 1e-12)
    float disc_logabs = logaddexp_f(logdet, LOG_DISC_EPS) - LOG1P_LEAD;
    float log_softabs = 0.5f * logaddexp_f(2.f * disc_logabs, LOG_DELTA2);
    float log_softabs_eps = logaddexp_f(log_softabs, LOG_DISC_EPS);
    float w = __expf(-log_softabs_eps * 0.125f);      // /N_DEG = /8

    return make_float3(speed * w, sp2, ac2);
}

__global__ __launch_bounds__(BLK, 1) void bez_coop_kernel(
    const float* __restrict__ P0, const float* __restrict__ Pd,
    const float* __restrict__ Pmid, const float* __restrict__ ts,
    float* __restrict__ partial, float* __restrict__ out)
{
    __shared__ float sP[8][8][2];
    __shared__ v2f sA2[8][8];       // monomial coeffs: T_j(t) = sum_m A[m][j] t^m
    __shared__ float sp1[13][8];    // per-(d,j) partials of |T'|^2 poly
    __shared__ float sp2p[11][8];   // per-(d,j) partials of |T''|^2 poly
    __shared__ v2f sPA[13];         // packed (|T'|^2 coeff, |T''|^2 coeff)
    __shared__ float red[4][3];

    const int tid = threadIdx.x;
    const int gidA = blockIdx.x * BLK + tid;
    const int gidB = gidA + (M_SAMPLES / 2);
    const float tA = ts[gidA];
    const float tB = ts[gidB];

    if (tid < 16) { sP[0][tid >> 1][tid & 1] = P0[tid]; sP[7][tid >> 1][tid & 1] = Pd[tid]; }
    if (tid < 96) { int r = tid / 16, rem = tid % 16; sP[1 + r][rem >> 1][rem & 1] = Pmid[tid]; }
    __syncthreads();
    // Bezier -> monomial: A_m = C(7,m) * sum_{k<=m} (-1)^(m-k) C(m,k) P_k
    if (tid < 64) {
        int m = tid >> 3, j = tid & 7;
        float aR = 0.f, aI = 0.f;
        float sgn = (m & 1) ? -1.f : 1.f;           // (-1)^m at k=0
        for (int k = 0; k <= m; ++k) {
            aR += sgn * BINOM[m][k] * sP[k][j][0];
            aI += sgn * BINOM[m][k] * sP[k][j][1];
            sgn = -sgn;
        }
        sA2[m][j] = (v2f){BINOM[7][m] * aR, BINOM[7][m] * aI};
    }
    __syncthreads();
    // Parallel partials: lane (d,j) sums over m — short, wide, no serial chain.
    if (tid < 104) {                                  // |T'|^2: d = 0..12
        int d = tid >> 3, j = tid & 7;
        int lo = d > 6 ? d - 6 : 0, hi = d < 6 ? d : 6;
        float s = 0.f;
        for (int m = lo; m <= hi; ++m) {
            int mp = d - m;
            float wgt = (float)((m + 1) * (mp + 1));
            v2f a = sA2[m + 1][j], b = sA2[mp + 1][j];
            s += wgt * (a.x * b.x + a.y * b.y);
        }
        sp1[d][j] = s;
    }
    if (tid >= 128 && tid < 216) {                    // |T''|^2: d = 0..10
        int d = (tid - 128) >> 3, j = (tid - 128) & 7;
        int lo = d > 5 ? d - 5 : 0, hi = d < 5 ? d : 5;
        float s = 0.f;
        for (int m = lo; m <= hi; ++m) {
            int mp = d - m;
            float wgt = (float)((m + 2) * (m + 1) * (mp + 2) * (mp + 1));
            v2f a = sA2[m + 2][j], b = sA2[mp + 2][j];
            s += wgt * (a.x * b.x + a.y * b.y);
        }
        sp2p[d][j] = s;
    }
    __syncthreads();
    if (tid < 13) {
        float s1 = 0.f, s2 = 0.f;
        for (int j = 0; j < 8; ++j) s1 += sp1[tid][j];
        if (tid <= 10) { for (int j = 0; j < 8; ++j) s2 += sp2p[tid][j]; }
        sPA[tid] = (v2f){s1, s2};
    }
    __syncthreads();

    // Two independent sample pipelines — compiler interleaves for ILP.
    float3 A = eval_sample(tA, sA2, sPA);
    float3 Bv = eval_sample(tB, sA2, sPA);

    float v1 = A.x + Bv.x, v2 = A.y + Bv.y, v3 = A.z + Bv.z;
#pragma unroll
    for (int off = 32; off; off >>= 1) {
        v1 += __shfl_down(v1, off);
        v2 += __shfl_down(v2, off);
        v3 += __shfl_down(v3, off);
    }
    const int wid = tid >> 6, lane = tid & 63;
    if (lane == 0) { red[wid][0] = v1; red[wid][1] = v2; red[wid][2] = v3; }
    __syncthreads();
    if (tid == 0) {
        float s1 = 0.f, s2 = 0.f, s3 = 0.f;
        for (int w2 = 0; w2 < 4; ++w2) { s1 += red[w2][0]; s2 += red[w2][1]; s3 += red[w2][2]; }
        partial[blockIdx.x * 3 + 0] = s1;
        partial[blockIdx.x * 3 + 1] = s2;
        partial[blockIdx.x * 3 + 2] = s3;
    }

    // ---- grid-wide barrier, then block 0 reduces the 256 partial triples ----
    cg::this_grid().sync();

    if (blockIdx.x == 0) {
        float s1 = partial[tid * 3 + 0];
        float s2 = partial[tid * 3 + 1];
        float s3 = partial[tid * 3 + 2];
#pragma unroll
        for (int off = 32; off; off >>= 1) {
            s1 += __shfl_down(s1, off);
            s2 += __shfl_down(s2, off);
            s3 += __shfl_down(s3, off);
        }
        if (lane == 0) { red[wid][0] = s1; red[wid][1] = s2; red[wid][2] = s3; }
        __syncthreads();
        if (tid == 0) {
            float t1 = 0.f, t2 = 0.f, t3 = 0.f;
            for (int w2 = 0; w2 < 4; ++w2) { t1 += red[w2][0]; t2 += red[w2][1]; t3 += red[w2][2]; }
            const float Mf = (float)M_SAMPLES;
            out[0] = t1 / Mf + 0.1f * sqrtf(t2 / Mf) + 0.01f * sqrtf(t3 / Mf);
        }
    }
}

extern "C" void kernel_launch(void* const* d_in, const int* in_sizes, int n_in,
                              void* d_out, int out_size, void* d_ws, size_t ws_size,
                              hipStream_t stream) {
    const float* P0   = (const float*)d_in[0];   // (8,2)
    const float* Pd   = (const float*)d_in[1];   // (8,2)
    const float* Pmid = (const float*)d_in[2];   // (6,8,2)
    const float* ts   = (const float*)d_in[3];   // (131072,)
    float* out = (float*)d_out;
    float* partial = (float*)d_ws;               // NBLK*3 floats

    void* args[] = { (void*)&P0, (void*)&Pd, (void*)&Pmid, (void*)&ts,
                     (void*)&partial, (void*)&out };
    hipLaunchCooperativeKernel((const void*)bez_coop_kernel,
                               dim3(NBLK), dim3(BLK), args, 0, stream);
}

// Round 13
// 12.895 us; speedup vs baseline: 3.6409x; 3.6409x over previous
//
#include <hip/hip_runtime.h>
#include <math.h>

#define M_SAMPLES 131072
#define BLK 256
#define NBLK (M_SAMPLES / (BLK * 2))   // 256 blocks, 2 samples/thread

typedef float v2f __attribute__((ext_vector_type(2)));

__device__ __forceinline__ v2f swapneg(v2f b) { return (v2f){-b.y, b.x}; }

__device__ __forceinline__ float logaddexp_f(float a, float b) {
    float m = fmaxf(a, b);
    float d = fminf(a, b) - m;
    return m + __logf(1.f + __expf(d));
}

// C(m,k) table (rodata; runtime-indexed loads are memory, not registers)
__device__ const float BINOM[8][8] = {
  {1,0,0,0,0,0,0,0},{1,1,0,0,0,0,0,0},{1,2,1,0,0,0,0,0},{1,3,3,1,0,0,0,0},
  {1,4,6,4,1,0,0,0},{1,5,10,10,5,1,0,0},{1,6,15,20,15,6,1,0},{1,7,21,35,35,21,7,1}};

// Full per-sample pipeline on REGISTER-resident coefficients (CA, CP):
// Horner -> Bezout -> LDL -> weights. All arrays statically indexed.
__device__ __forceinline__ float3 eval_sample(
    float t, const v2f (&CA)[8][8], const v2f (&CP)[13])
{
    // T_j via Horner (ascending storage f[7-j] = T_j), monic f_8 = 1.
    v2f f[9];
#pragma unroll
    for (int j = 0; j < 8; ++j) {
        v2f p = CA[7][j];
#pragma unroll
        for (int m = 6; m >= 0; --m) p = p * t + CA[m][j];
        f[7 - j] = p;
    }
    f[8] = (v2f){1.f, 0.f};

    // speed^2 / accel^2: one packed real Horner
    v2f pa = CP[12];
#pragma unroll
    for (int d = 11; d >= 0; --d) pa = pa * t + CP[d];
    const float sp2 = fmaxf(pa.x, 0.f);
    const float ac2 = fmaxf(pa.y, 0.f);
    const float speed = sqrtf(sp2);

    // u_k = k * f_k  (g_j = f'_j = u_{j+1}); us = swapneg(u) for complex mul
    v2f u[9], us[9];
#pragma unroll
    for (int k = 1; k < 9; ++k) { u[k] = (float)k * f[k]; us[k] = swapneg(u[k]); }

    // Bezout matrix B (8x8 complex symmetric): |det B| = |Res(f,f')| (f monic).
    v2f B[8][8], c[8][8];
#pragma unroll
    for (int j = 0; j < 8; ++j) B[7][j] = u[j + 1];
#pragma unroll
    for (int i = 7; i >= 1; --i) {
#pragma unroll
        for (int j = 0; j < i; ++j) {   // fresh pairs (j, i)
            c[j][i] = (f[j].x * u[i + 1] + f[j].y * us[i + 1])
                    - (f[i].x * u[j + 1] + f[i].y * us[j + 1]);
        }
#pragma unroll
        for (int j = 0; j < 8; ++j) {
            v2f cr;
            if (i < j)      cr = c[i][j];
            else if (i > j) cr = -c[j][i];
            else            cr = (v2f){0.f, 0.f};
            if (j >= 1) cr += B[i][j - 1];
            B[i - 1][j] = cr;
        }
    }

    // Pivot-free complex-symmetric LDL^T, upper triangle (R5-identical order).
    float logm = 1.f; int loge = 0;
#pragma unroll
    for (int k = 0; k < 8; ++k) {
        v2f d = B[k][k];
        float pm2 = d.x * d.x + d.y * d.y;
        unsigned ub = __float_as_uint(pm2);
        loge += (int)(ub >> 23) - 126;
        logm *= __uint_as_float((ub & 0x007fffffu) | 0x3f000000u);  // [0.5,1)
        if (k < 7) {
            float is = __builtin_amdgcn_rcpf(pm2);
            is = (pm2 > 1e-30f) ? is : 0.f;
            v2f iv = (v2f){d.x * is, -d.y * is};          // 1/d
            v2f ivs = swapneg(iv);
            v2f w[8], bs[8];
#pragma unroll
            for (int i = k + 1; i < 8; ++i) {
                v2f a = B[k][i];                          // A[i][k] by symmetry
                w[i] = a.x * iv + a.y * ivs;              // w_i = a (x) 1/d
                bs[i] = swapneg(a);
            }
#pragma unroll
            for (int i = k + 1; i < 8; ++i) {
#pragma unroll
                for (int j = i; j < 8; ++j) {
                    B[i][j] = B[i][j] - w[i].x * B[k][j] - w[i].y * bs[j];
                }
            }
        }
    }
    float logdet = 0.5f * (__logf(logm) + (float)loge * 0.69314718055994531f);

    const float LOG_DISC_EPS = -27.63102111592855f;   // ln 1e-12
    const float LOG_DELTA2  = -27.63102111592855f;    // 2 ln 1e-6
    const float LOG1P_LEAD  = 1e-12f;                 // log(1 + 1e-12)
    float disc_logabs = logaddexp_f(logdet, LOG_DISC_EPS) - LOG1P_LEAD;
    float log_softabs = 0.5f * logaddexp_f(2.f * disc_logabs, LOG_DELTA2);
    float log_softabs_eps = logaddexp_f(log_softabs, LOG_DISC_EPS);
    float w = __expf(-log_softabs_eps * 0.125f);      // /N_DEG = /8

    return make_float3(speed * w, sp2, ac2);
}

__global__ __launch_bounds__(BLK, 1) void bez_main_kernel(
    const float* __restrict__ P0, const float* __restrict__ Pd,
    const float* __restrict__ Pmid, const float* __restrict__ ts,
    float* __restrict__ partial)
{
    __shared__ float sP[8][8][2];
    __shared__ v2f sA2[8][8];       // monomial coeffs: T_j(t) = sum_m A[m][j] t^m
    __shared__ float sp1[13][8];    // per-(d,j) partials of |T'|^2 poly
    __shared__ float sp2p[11][8];   // per-(d,j) partials of |T''|^2 poly
    __shared__ v2f sPA[13];         // packed (|T'|^2 coeff, |T''|^2 coeff)
    __shared__ float red[4][3];

    const int tid = threadIdx.x;
    const int gidA = blockIdx.x * BLK + tid;
    const int gidB = gidA + (M_SAMPLES / 2);
    const float tA = ts[gidA];
    const float tB = ts[gidB];

    if (tid < 16) { sP[0][tid >> 1][tid & 1] = P0[tid]; sP[7][tid >> 1][tid & 1] = Pd[tid]; }
    if (tid < 96) { int r = tid / 16, rem = tid % 16; sP[1 + r][rem >> 1][rem & 1] = Pmid[tid]; }
    __syncthreads();
    // Bezier -> monomial: A_m = C(7,m) * sum_{k<=m} (-1)^(m-k) C(m,k) P_k
    if (tid < 64) {
        int m = tid >> 3, j = tid & 7;
        float aR = 0.f, aI = 0.f;
        float sgn = (m & 1) ? -1.f : 1.f;           // (-1)^m at k=0
        for (int k = 0; k <= m; ++k) {
            aR += sgn * BINOM[m][k] * sP[k][j][0];
            aI += sgn * BINOM[m][k] * sP[k][j][1];
            sgn = -sgn;
        }
        sA2[m][j] = (v2f){BINOM[7][m] * aR, BINOM[7][m] * aI};
    }
    __syncthreads();
    // Parallel partials: lane (d,j) sums over m — short, wide, no serial chain.
    if (tid < 104) {                                  // |T'|^2: d = 0..12
        int d = tid >> 3, j = tid & 7;
        int lo = d > 6 ? d - 6 : 0, hi = d < 6 ? d : 6;
        float s = 0.f;
        for (int m = lo; m <= hi; ++m) {
            int mp = d - m;
            float wgt = (float)((m + 1) * (mp + 1));
            v2f a = sA2[m + 1][j], b = sA2[mp + 1][j];
            s += wgt * (a.x * b.x + a.y * b.y);
        }
        sp1[d][j] = s;
    }
    if (tid >= 128 && tid < 216) {                    // |T''|^2: d = 0..10
        int d = (tid - 128) >> 3, j = (tid - 128) & 7;
        int lo = d > 5 ? d - 5 : 0, hi = d < 5 ? d : 5;
        float s = 0.f;
        for (int m = lo; m <= hi; ++m) {
            int mp = d - m;
            float wgt = (float)((m + 2) * (m + 1) * (mp + 2) * (mp + 1));
            v2f a = sA2[m + 2][j], b = sA2[mp + 2][j];
            s += wgt * (a.x * b.x + a.y * b.y);
        }
        sp2p[d][j] = s;
    }
    __syncthreads();
    if (tid < 13) {
        float s1 = 0.f, s2 = 0.f;
        for (int j = 0; j < 8; ++j) s1 += sp1[tid][j];
        if (tid <= 10) { for (int j = 0; j < 8; ++j) s2 += sp2p[tid][j]; }
        sPA[tid] = (v2f){s1, s2};
    }
    __syncthreads();

    // ---- Hoist wave-uniform coefficients into registers ONCE ----
    // 77 independent broadcast LDS reads, one wait; both samples then run
    // entirely on the register file (no per-sample LDS latency).
    v2f CA[8][8];
#pragma unroll
    for (int m = 0; m < 8; ++m)
#pragma unroll
        for (int j = 0; j < 8; ++j) CA[m][j] = sA2[m][j];
    v2f CP[13];
#pragma unroll
    for (int d = 0; d < 13; ++d) CP[d] = sPA[d];

    // Two sample pipelines (sequential; compiler interleaves within pressure).
    float3 A = eval_sample(tA, CA, CP);
    float3 Bv = eval_sample(tB, CA, CP);

    float v1 = A.x + Bv.x, v2 = A.y + Bv.y, v3 = A.z + Bv.z;
#pragma unroll
    for (int off = 32; off; off >>= 1) {
        v1 += __shfl_down(v1, off);
        v2 += __shfl_down(v2, off);
        v3 += __shfl_down(v3, off);
    }
    const int wid = tid >> 6, lane = tid & 63;
    if (lane == 0) { red[wid][0] = v1; red[wid][1] = v2; red[wid][2] = v3; }
    __syncthreads();
    if (tid == 0) {
        float s1 = 0.f, s2 = 0.f, s3 = 0.f;
        for (int w2 = 0; w2 < 4; ++w2) { s1 += red[w2][0]; s2 += red[w2][1]; s3 += red[w2][2]; }
        partial[blockIdx.x * 3 + 0] = s1;
        partial[blockIdx.x * 3 + 1] = s2;
        partial[blockIdx.x * 3 + 2] = s3;
    }
}

__global__ __launch_bounds__(64) void bez_finalize_kernel(
    const float* __restrict__ partial, float* __restrict__ out)
{
    const int lane = threadIdx.x;
    float s1 = 0.f, s2 = 0.f, s3 = 0.f;
#pragma unroll
    for (int k = 0; k < NBLK / 64; ++k) {
        const int b = lane + k * 64;
        s1 += partial[b * 3 + 0];
        s2 += partial[b * 3 + 1];
        s3 += partial[b * 3 + 2];
    }
#pragma unroll
    for (int off = 32; off; off >>= 1) {
        s1 += __shfl_down(s1, off);
        s2 += __shfl_down(s2, off);
        s3 += __shfl_down(s3, off);
    }
    if (lane == 0) {
        const float Mf = (float)M_SAMPLES;
        out[0] = s1 / Mf + 0.1f * sqrtf(s2 / Mf) + 0.01f * sqrtf(s3 / Mf);
    }
}

extern "C" void kernel_launch(void* const* d_in, const int* in_sizes, int n_in,
                              void* d_out, int out_size, void* d_ws, size_t ws_size,
                              hipStream_t stream) {
    const float* P0   = (const float*)d_in[0];   // (8,2)
    const float* Pd   = (const float*)d_in[1];   // (8,2)
    const float* Pmid = (const float*)d_in[2];   // (6,8,2)
    const float* ts   = (const float*)d_in[3];   // (131072,)
    float* out = (float*)d_out;
    float* partial = (float*)d_ws;               // NBLK*3 floats

    bez_main_kernel<<<NBLK, BLK, 0, stream>>>(P0, Pd, Pmid, ts, partial);
    bez_finalize_kernel<<<1, 64, 0, stream>>>(partial, out);
}

// Round 14
// 12.640 us; speedup vs baseline: 3.7144x; 1.0202x over previous
//
#include <hip/hip_runtime.h>
#include <math.h>

#define M_SAMPLES 131072
#define BLK 256
#define NBLK (M_SAMPLES / (BLK * 2))   // 256 blocks, 2 samples/thread (SoA-packed)

typedef float v2f __attribute__((ext_vector_type(2)));

__device__ __forceinline__ v2f vsplat(float s) { return (v2f){s, s}; }

__device__ __forceinline__ float logaddexp_f(float a, float b) {
    float m = fmaxf(a, b);
    float d = fminf(a, b) - m;
    return m + __logf(1.f + __expf(d));
}

// C(m,k) table (rodata; runtime-indexed loads are memory, not registers)
__device__ const float BINOM[8][8] = {
  {1,0,0,0,0,0,0,0},{1,1,0,0,0,0,0,0},{1,2,1,0,0,0,0,0},{1,3,3,1,0,0,0,0},
  {1,4,6,4,1,0,0,0},{1,5,10,10,5,1,0,0},{1,6,15,20,15,6,1,0},{1,7,21,35,35,21,7,1}};

__global__ __launch_bounds__(BLK, 1) void bez_main_kernel(
    const float* __restrict__ P0, const float* __restrict__ Pd,
    const float* __restrict__ Pmid, const float* __restrict__ ts,
    float* __restrict__ partial)
{
    __shared__ float sP[8][8][2];
    __shared__ float sAr[8][8];     // monomial coeffs (real):  T_j = sum_m A[m][j] t^m
    __shared__ float sAi[8][8];     // monomial coeffs (imag)
    __shared__ float sp1[13][8];    // per-(d,j) partials of |T'|^2 poly
    __shared__ float sp2p[11][8];   // per-(d,j) partials of |T''|^2 poly
    __shared__ float sSP2[13];      // sum_j |T'_j|^2 : real poly deg 12
    __shared__ float sAC2[11];      // sum_j |T''_j|^2: real poly deg 10
    __shared__ float red[4][3];

    const int tid = threadIdx.x;
    const int gidA = blockIdx.x * BLK + tid;
    const int gidB = gidA + (M_SAMPLES / 2);
    const v2f tt = (v2f){ts[gidA], ts[gidB]};   // SoA over the 2 samples

    if (tid < 16) { sP[0][tid >> 1][tid & 1] = P0[tid]; sP[7][tid >> 1][tid & 1] = Pd[tid]; }
    if (tid < 96) { int r = tid / 16, rem = tid % 16; sP[1 + r][rem >> 1][rem & 1] = Pmid[tid]; }
    __syncthreads();
    // Bezier -> monomial: A_m = C(7,m) * sum_{k<=m} (-1)^(m-k) C(m,k) P_k
    if (tid < 64) {
        int m = tid >> 3, j = tid & 7;
        float aR = 0.f, aI = 0.f;
        float sgn = (m & 1) ? -1.f : 1.f;           // (-1)^m at k=0
        for (int k = 0; k <= m; ++k) {
            aR += sgn * BINOM[m][k] * sP[k][j][0];
            aI += sgn * BINOM[m][k] * sP[k][j][1];
            sgn = -sgn;
        }
        sAr[m][j] = BINOM[7][m] * aR;
        sAi[m][j] = BINOM[7][m] * aI;
    }
    __syncthreads();
    // Parallel partials: lane (d,j) sums over m — short, wide, no serial chain.
    if (tid < 104) {                                  // |T'|^2: d = 0..12
        int d = tid >> 3, j = tid & 7;
        int lo = d > 6 ? d - 6 : 0, hi = d < 6 ? d : 6;
        float s = 0.f;
        for (int m = lo; m <= hi; ++m) {
            int mp = d - m;
            float wgt = (float)((m + 1) * (mp + 1));
            s += wgt * (sAr[m + 1][j] * sAr[mp + 1][j] + sAi[m + 1][j] * sAi[mp + 1][j]);
        }
        sp1[d][j] = s;
    }
    if (tid >= 128 && tid < 216) {                    // |T''|^2: d = 0..10
        int d = (tid - 128) >> 3, j = (tid - 128) & 7;
        int lo = d > 5 ? d - 5 : 0, hi = d < 5 ? d : 5;
        float s = 0.f;
        for (int m = lo; m <= hi; ++m) {
            int mp = d - m;
            float wgt = (float)((m + 2) * (m + 1) * (mp + 2) * (mp + 1));
            s += wgt * (sAr[m + 2][j] * sAr[mp + 2][j] + sAi[m + 2][j] * sAi[mp + 2][j]);
        }
        sp2p[d][j] = s;
    }
    __syncthreads();
    if (tid < 13) {
        float s = 0.f;
        for (int j = 0; j < 8; ++j) s += sp1[tid][j];
        sSP2[tid] = s;
    }
    if (tid >= 64 && tid < 75) {
        float s = 0.f;
        for (int j = 0; j < 8; ++j) s += sp2p[tid - 64][j];
        sAC2[tid - 64] = s;
    }
    __syncthreads();

    // ---- Both samples in ONE chain: every v2f lane-pair = (sampleA, sampleB) ----
    // T_j via Horner (ascending storage f[7-j] = T_j), monic f_8 = 1.
    v2f fre[9], fim[9];
#pragma unroll
    for (int j = 0; j < 8; ++j) {
        v2f pre = vsplat(sAr[7][j]), pim = vsplat(sAi[7][j]);
#pragma unroll
        for (int m = 6; m >= 0; --m) {
            pre = pre * tt + vsplat(sAr[m][j]);
            pim = pim * tt + vsplat(sAi[m][j]);
        }
        fre[7 - j] = pre; fim[7 - j] = pim;
    }
    fre[8] = vsplat(1.f); fim[8] = vsplat(0.f);

    // speed^2 / accel^2 real Horners (both samples per instruction)
    v2f sp = vsplat(sSP2[12]);
#pragma unroll
    for (int d = 11; d >= 0; --d) sp = sp * tt + vsplat(sSP2[d]);
    sp.x = fmaxf(sp.x, 0.f); sp.y = fmaxf(sp.y, 0.f);
    v2f ac = vsplat(sAC2[10]);
#pragma unroll
    for (int d = 9; d >= 0; --d) ac = ac * tt + vsplat(sAC2[d]);
    ac.x = fmaxf(ac.x, 0.f); ac.y = fmaxf(ac.y, 0.f);
    const float speedA = sqrtf(sp.x), speedB = sqrtf(sp.y);

    // u_k = k * f_k  (g_j = f'_j = u_{j+1})
    v2f ure[9], uim[9];
#pragma unroll
    for (int k = 1; k < 9; ++k) { ure[k] = (float)k * fre[k]; uim[k] = (float)k * fim[k]; }

    // Bezout matrix B (8x8 complex symmetric): |det B| = |Res(f,f')| (f monic).
    // B[7][j] = u_{j+1} ; B[i-1][j] = c_{ij} + B[i][j-1], c computed lazily.
    v2f Bre[8][8], Bim[8][8], cre[8][8], cim[8][8];
#pragma unroll
    for (int j = 0; j < 8; ++j) { Bre[7][j] = ure[j + 1]; Bim[7][j] = uim[j + 1]; }
#pragma unroll
    for (int i = 7; i >= 1; --i) {
#pragma unroll
        for (int j = 0; j < i; ++j) {   // fresh pairs (j, i):  c_{j,i} = f_j (x) u_{i+1} - f_i (x) u_{j+1}
            cre[j][i] = fre[j] * ure[i + 1] - fim[j] * uim[i + 1]
                      - fre[i] * ure[j + 1] + fim[i] * uim[j + 1];
            cim[j][i] = fre[j] * uim[i + 1] + fim[j] * ure[i + 1]
                      - fre[i] * uim[j + 1] - fim[i] * ure[j + 1];
        }
#pragma unroll
        for (int j = 0; j < 8; ++j) {
            v2f cr, ci;
            if (i < j)      { cr = cre[i][j];  ci = cim[i][j]; }
            else if (i > j) { cr = -cre[j][i]; ci = -cim[j][i]; }
            else            { cr = vsplat(0.f); ci = vsplat(0.f); }
            if (j >= 1) { cr += Bre[i][j - 1]; ci += Bim[i][j - 1]; }
            Bre[i - 1][j] = cr; Bim[i - 1][j] = ci;
        }
    }

    // Pivot-free complex-symmetric LDL^T, upper triangle (R5-identical order).
    // log|det| via mantissa-product + exponent-sum, per lane-pair.
    v2f logm = vsplat(1.f); int logeA = 0, logeB = 0;
#pragma unroll
    for (int k = 0; k < 8; ++k) {
        v2f dre = Bre[k][k], dim = Bim[k][k];
        v2f pm2 = dre * dre + dim * dim;
        {
            unsigned ua = __float_as_uint(pm2.x);
            logeA += (int)(ua >> 23) - 126;
            logm.x *= __uint_as_float((ua & 0x007fffffu) | 0x3f000000u);
            unsigned ub = __float_as_uint(pm2.y);
            logeB += (int)(ub >> 23) - 126;
            logm.y *= __uint_as_float((ub & 0x007fffffu) | 0x3f000000u);
        }
        if (k < 7) {
            float isA = __builtin_amdgcn_rcpf(pm2.x); isA = (pm2.x > 1e-30f) ? isA : 0.f;
            float isB = __builtin_amdgcn_rcpf(pm2.y); isB = (pm2.y > 1e-30f) ? isB : 0.f;
            const v2f is = (v2f){isA, isB};
            const v2f ivre = dre * is, ivim = -dim * is;      // 1/d
            v2f wre[8], wim[8];
#pragma unroll
            for (int i = k + 1; i < 8; ++i) {
                v2f are = Bre[k][i], aim = Bim[k][i];          // A[i][k] by symmetry
                wre[i] = are * ivre - aim * ivim;              // w_i = a (x) 1/d
                wim[i] = are * ivim + aim * ivre;
            }
#pragma unroll
            for (int i = k + 1; i < 8; ++i) {
#pragma unroll
                for (int j = i; j < 8; ++j) {
                    v2f bre = Bre[k][j], bim = Bim[k][j];
                    Bre[i][j] = Bre[i][j] - (wre[i] * bre - wim[i] * bim);
                    Bim[i][j] = Bim[i][j] - (wre[i] * bim + wim[i] * bre);
                }
            }
        }
    }
    const float LN2 = 0.69314718055994531f;
    float logdetA = 0.5f * (__logf(logm.x) + (float)logeA * LN2);
    float logdetB = 0.5f * (__logf(logm.y) + (float)logeB * LN2);

    const float LOG_DISC_EPS = -27.63102111592855f;   // ln 1e-12
    const float LOG_DELTA2  = -27.63102111592855f;    // 2 ln 1e-6
    const float LOG1P_LEAD  = 1e-12f;                 // log(1 + 1e-12)
    float dlA = logaddexp_f(logdetA, LOG_DISC_EPS) - LOG1P_LEAD;
    float lsA = 0.5f * logaddexp_f(2.f * dlA, LOG_DELTA2);
    float leA = logaddexp_f(lsA, LOG_DISC_EPS);
    float wA = __expf(-leA * 0.125f);                 // /N_DEG = /8
    float dlB = logaddexp_f(logdetB, LOG_DISC_EPS) - LOG1P_LEAD;
    float lsB = 0.5f * logaddexp_f(2.f * dlB, LOG_DELTA2);
    float leB = logaddexp_f(lsB, LOG_DISC_EPS);
    float wB = __expf(-leB * 0.125f);

    float v1 = speedA * wA + speedB * wB;
    float v2 = sp.x + sp.y;
    float v3 = ac.x + ac.y;
#pragma unroll
    for (int off = 32; off; off >>= 1) {
        v1 += __shfl_down(v1, off);
        v2 += __shfl_down(v2, off);
        v3 += __shfl_down(v3, off);
    }
    const int wid = tid >> 6, lane = tid & 63;
    if (lane == 0) { red[wid][0] = v1; red[wid][1] = v2; red[wid][2] = v3; }
    __syncthreads();
    if (tid == 0) {
        float s1 = 0.f, s2 = 0.f, s3 = 0.f;
        for (int w2 = 0; w2 < 4; ++w2) { s1 += red[w2][0]; s2 += red[w2][1]; s3 += red[w2][2]; }
        partial[blockIdx.x * 3 + 0] = s1;
        partial[blockIdx.x * 3 + 1] = s2;
        partial[blockIdx.x * 3 + 2] = s3;
    }
}

__global__ __launch_bounds__(64) void bez_finalize_kernel(
    const float* __restrict__ partial, float* __restrict__ out)
{
    const int lane = threadIdx.x;
    float s1 = 0.f, s2 = 0.f, s3 = 0.f;
#pragma unroll
    for (int k = 0; k < NBLK / 64; ++k) {
        const int b = lane + k * 64;
        s1 += partial[b * 3 + 0];
        s2 += partial[b * 3 + 1];
        s3 += partial[b * 3 + 2];
    }
#pragma unroll
    for (int off = 32; off; off >>= 1) {
        s1 += __shfl_down(s1, off);
        s2 += __shfl_down(s2, off);
        s3 += __shfl_down(s3, off);
    }
    if (lane == 0) {
        const float Mf = (float)M_SAMPLES;
        out[0] = s1 / Mf + 0.1f * sqrtf(s2 / Mf) + 0.01f * sqrtf(s3 / Mf);
    }
}

extern "C" void kernel_launch(void* const* d_in, const int* in_sizes, int n_in,
                              void* d_out, int out_size, void* d_ws, size_t ws_size,
                              hipStream_t stream) {
    const float* P0   = (const float*)d_in[0];   // (8,2)
    const float* Pd   = (const float*)d_in[1];   // (8,2)
    const float* Pmid = (const float*)d_in[2];   // (6,8,2)
    const float* ts   = (const float*)d_in[3];   // (131072,)
    float* out = (float*)d_out;
    float* partial = (float*)d_ws;               // NBLK*3 floats

    bez_main_kernel<<<NBLK, BLK, 0, stream>>>(P0, Pd, Pmid, ts, partial);
    bez_finalize_kernel<<<1, 64, 0, stream>>>(partial, out);
}